// Round 4
// baseline (821.520 us; speedup 1.0000x reference)
//
#include <hip/hip_runtime.h>

#define SS 512
#define DD 768
#define TT 64

// ---------------------------------------------------------------------------
// Kernel 1: emissions GEMM  em[b*512+s][t] = sum_d x[b,s,d]*W[t,d] + bias[t]
// fp32 vector FMA, 128x64 tile, 256 threads, thread tile 8x4. (~20-25 us)
// ---------------------------------------------------------------------------
__global__ __launch_bounds__(256) void emis_gemm(
    const float* __restrict__ X, const float* __restrict__ W,
    const float* __restrict__ bias, float* __restrict__ em)
{
    __shared__ __align__(16) float Xs[16][132];
    __shared__ __align__(16) float Ws[16][68];

    const int tid = threadIdx.x;
    const int m0  = blockIdx.x * 128;
    const int tm  = tid >> 4;
    const int tn  = tid & 15;
    const int lm  = tid >> 2;
    const int lkq = tid & 3;
    const int wt  = tid & 63;
    const int wkq = tid >> 6;

    float acc[8][4];
#pragma unroll
    for (int i = 0; i < 8; i++)
#pragma unroll
        for (int j = 0; j < 4; j++) acc[i][j] = 0.f;

    float4 xr0, xr1, wr;
    xr0 = *(const float4*)&X[(size_t)(m0 + lm) * DD + lkq * 4];
    xr1 = *(const float4*)&X[(size_t)(m0 + lm + 64) * DD + lkq * 4];
    wr  = *(const float4*)&W[(size_t)wt * DD + wkq * 4];

    for (int t = 0; t < 48; t++) {
        Xs[lkq * 4 + 0][lm] = xr0.x;  Xs[lkq * 4 + 1][lm] = xr0.y;
        Xs[lkq * 4 + 2][lm] = xr0.z;  Xs[lkq * 4 + 3][lm] = xr0.w;
        Xs[lkq * 4 + 0][lm + 64] = xr1.x;  Xs[lkq * 4 + 1][lm + 64] = xr1.y;
        Xs[lkq * 4 + 2][lm + 64] = xr1.z;  Xs[lkq * 4 + 3][lm + 64] = xr1.w;
        Ws[wkq * 4 + 0][wt] = wr.x;  Ws[wkq * 4 + 1][wt] = wr.y;
        Ws[wkq * 4 + 2][wt] = wr.z;  Ws[wkq * 4 + 3][wt] = wr.w;
        __syncthreads();

        if (t < 47) {
            const int k0 = (t + 1) * 16;
            xr0 = *(const float4*)&X[(size_t)(m0 + lm) * DD + k0 + lkq * 4];
            xr1 = *(const float4*)&X[(size_t)(m0 + lm + 64) * DD + k0 + lkq * 4];
            wr  = *(const float4*)&W[(size_t)wt * DD + k0 + wkq * 4];
        }

#pragma unroll
        for (int k = 0; k < 16; k++) {
            float a[8], bv[4];
            *(float4*)&a[0] = *(const float4*)&Xs[k][tm * 8];
            *(float4*)&a[4] = *(const float4*)&Xs[k][tm * 8 + 4];
            *(float4*)&bv[0] = *(const float4*)&Ws[k][tn * 4];
#pragma unroll
            for (int i = 0; i < 8; i++)
#pragma unroll
                for (int j = 0; j < 4; j++)
                    acc[i][j] = fmaf(a[i], bv[j], acc[i][j]);
        }
        __syncthreads();
    }

    const float4 bv4 = *(const float4*)&bias[tn * 4];
#pragma unroll
    for (int i = 0; i < 8; i++) {
        const size_t row = (size_t)(m0 + tm * 8 + i);
        float4 o;
        o.x = acc[i][0] + bv4.x;  o.y = acc[i][1] + bv4.y;
        o.z = acc[i][2] + bv4.z;  o.w = acc[i][3] + bv4.w;
        *(float4*)&em[row * TT + tn * 4] = o;
    }
}

// ---------------------------------------------------------------------------
// Kernel 2: Viterbi scan. ONE WAVE PER BATCH (64 blocks x 64 threads).
// lane = cur tag. Critical path per step = ds_read(scores) -> 2 adds ->
// v_max3 tree (depth 4, VALUE only) -> ds_write(new score) -> next reads.
// The argmax (backpointer) is computed AFTER the score write via a reverse
// first-index-equality scan, off the serial chain. Semantics exact:
// v = (score[prev]+trans)+em (reference rounding), vmax is bit-exact one of
// v[i], reverse scan returns smallest i with v[i]==vmax (numpy argmax).
// ---------------------------------------------------------------------------
__global__ __launch_bounds__(64, 1) void viterbi(
    const float* __restrict__ em, const float* __restrict__ trans,
    unsigned int* __restrict__ hist32, int* __restrict__ bestTag)
{
    __shared__ __align__(16) float sc_lds[TT];

    const int b    = blockIdx.x;
    const int lane = threadIdx.x;
    const float* emb = em + (size_t)b * SS * TT;
    unsigned int* hb = hist32 + (size_t)b * 128 * TT;

    float treg[TT];
#pragma unroll
    for (int p = 0; p < TT; p++) treg[p] = trans[p * TT + lane];

    const float em0 = emb[lane];
    sc_lds[lane] = em0;
    float cur_score = em0;
    unsigned int packed = 0;

    // emission prefetch ring (step s consumes em row s)
    float er0 = emb[1 * TT + lane];
    float er1 = emb[2 * TT + lane];
    float er2 = emb[3 * TT + lane];
    float er3 = emb[4 * TT + lane];

    // prime score reads for step 1 (DS FIFO: issued after the init write)
    float4 sq[16];
    {
        const float4* sb = (const float4*)sc_lds;
#pragma unroll
        for (int i = 0; i < 16; i++) sq[i] = sb[i];
    }

    auto step = [&](int s, float em_v) {
        // candidates (exact reference rounding: (score+trans)+em)
        float v[TT];
#pragma unroll
        for (int i = 0; i < 16; i++) {
            v[4 * i + 0] = (sq[i].x + treg[4 * i + 0]) + em_v;
            v[4 * i + 1] = (sq[i].y + treg[4 * i + 1]) + em_v;
            v[4 * i + 2] = (sq[i].z + treg[4 * i + 2]) + em_v;
            v[4 * i + 3] = (sq[i].w + treg[4 * i + 3]) + em_v;
        }
        // VALUE max via max3 tree (depth 4) -- critical path
        float t1[22];
#pragma unroll
        for (int i = 0; i < 21; i++)
            t1[i] = fmaxf(fmaxf(v[3 * i], v[3 * i + 1]), v[3 * i + 2]);
        t1[21] = v[63];
        float t2[8];
#pragma unroll
        for (int i = 0; i < 7; i++)
            t2[i] = fmaxf(fmaxf(t1[3 * i], t1[3 * i + 1]), t1[3 * i + 2]);
        t2[7] = t1[21];
        float t3[3];
        t3[0] = fmaxf(fmaxf(t2[0], t2[1]), t2[2]);
        t3[1] = fmaxf(fmaxf(t2[3], t2[4]), t2[5]);
        t3[2] = fmaxf(t2[6], t2[7]);
        const float vmax = fmaxf(fmaxf(t3[0], t3[1]), t3[2]);

        cur_score = vmax;
        sc_lds[lane] = vmax;               // ds_write: ends critical path
        if (s < 511) {                     // issue next step's reads NOW
            const float4* sb = (const float4*)sc_lds;
#pragma unroll
            for (int i = 0; i < 16; i++) sq[i] = sb[i];
        }
        // argmax: smallest i with v[i]==vmax (off critical path)
        int idx = 63;
#pragma unroll
        for (int i = 62; i >= 0; i--) idx = (v[i] == vmax) ? i : idx;

        packed |= (unsigned int)idx << ((s & 3) * 8);
        if ((s & 3) == 3) { hb[(s >> 2) * TT + lane] = packed; packed = 0u; }
    };

    for (int sb = 1; sb <= 505; sb += 4) {
        step(sb + 0, er0);  er0 = emb[(sb + 4) * TT + lane];
        step(sb + 1, er1);  er1 = emb[(sb + 5) * TT + lane];
        step(sb + 2, er2);  er2 = emb[(sb + 6) * TT + lane];
        step(sb + 3, er3);  er3 = emb[((sb + 7) <= 511 ? (sb + 7) : 511) * TT + lane];
    }
    step(509, er0);
    step(510, er1);
    step(511, er2);

    // final argmax across lanes (first-index ties)
    float fv = cur_score;
    int   fa = lane;
#pragma unroll
    for (int m = 1; m <= 32; m <<= 1) {
        const float vo = __shfl_xor(fv, m, 64);
        const int   ao = __shfl_xor(fa, m, 64);
        if (vo > fv || (vo == fv && ao < fa)) { fv = vo; fa = ao; }
    }
    if (lane == 0) bestTag[b] = fa;
}

// ---------------------------------------------------------------------------
// Kernel 3: backtrack via path doubling ENTIRELY IN LDS (2x32KB ping-pong).
// hist byte for (s,t) lives at ((s>>2)*64 + t)*4 + (s&3) within batch b.
// ---------------------------------------------------------------------------
__global__ __launch_bounds__(256) void backtrack(
    const unsigned int* __restrict__ hist32, const int* __restrict__ bestTag,
    int* __restrict__ out)
{
    __shared__ unsigned char A[511 * 64];
    __shared__ unsigned char Bf[511 * 64];

    const int b   = blockIdx.x;
    const int tid = threadIdx.x;
    const unsigned char* h8 = (const unsigned char*)(hist32 + (size_t)b * 128 * TT);

    // G[s][t] = tag at s given tag at s+1 = t ; init from hist[s+1]
    for (int idx = tid; idx < 511 * 64; idx += 256) {
        const int s = (idx >> 6) + 1;
        const int t = idx & 63;
        A[idx] = h8[((s >> 2) * 64 + t) * 4 + (s & 3)];
    }
    __syncthreads();

    unsigned char* curT = A;
    unsigned char* nxtT = Bf;
    for (int d = 1; d < 511; d <<= 1) {
        for (int idx = tid; idx < 511 * 64; idx += 256) {
            const int s = idx >> 6;
            const int t = idx & 63;
            unsigned char r;
            if (s + d >= 511) {
                r = curT[idx];
            } else {
                const unsigned char mid = curT[(s + d) * 64 + t];
                r = curT[s * 64 + mid];
            }
            nxtT[idx] = r;
        }
        __syncthreads();
        unsigned char* tmp = curT; curT = nxtT; nxtT = tmp;
    }

    const int bt = bestTag[b];
    for (int s = tid; s < SS; s += 256) {
        const int tag = (s == 511) ? bt : (int)curT[s * 64 + bt];
        out[(size_t)b * SS + s] = tag;
    }
}

// ---------------------------------------------------------------------------
extern "C" void kernel_launch(void* const* d_in, const int* in_sizes, int n_in,
                              void* d_out, int out_size, void* d_ws, size_t ws_size,
                              hipStream_t stream)
{
    const float* X     = (const float*)d_in[0];  // [64,512,768]
    const float* W     = (const float*)d_in[1];  // [64,768]
    const float* bias  = (const float*)d_in[2];  // [64]
    const float* trans = (const float*)d_in[3];  // [64,64]
    int* out = (int*)d_out;                      // [64,512] int32

    char* ws = (char*)d_ws;
    float*        em      = (float*)ws;                     // 8,388,608 B
    unsigned int* hist32  = (unsigned int*)(ws + 8388608);  // 2,097,152 B
    int*          bestTag = (int*)(ws + 10485760);          // 256 B

    emis_gemm<<<dim3(256), dim3(256), 0, stream>>>(X, W, bias, em);
    viterbi<<<dim3(64), dim3(64), 0, stream>>>(em, trans, hist32, bestTag);
    backtrack<<<dim3(64), dim3(256), 0, stream>>>(hist32, bestTag, out);
}

// Round 5
// 309.097 us; speedup vs baseline: 2.6578x; 2.6578x over previous
//
#include <hip/hip_runtime.h>

#define SS 512
#define DD 768
#define TT 64

// ---------------------------------------------------------------------------
// Kernel 1: emissions GEMM  em[b*512+s][t] = sum_d x[b,s,d]*W[t,d] + bias[t]
// fp32 vector FMA, 128x64 tile, 256 threads, thread tile 8x4. (~20-25 us)
// ---------------------------------------------------------------------------
__global__ __launch_bounds__(256) void emis_gemm(
    const float* __restrict__ X, const float* __restrict__ W,
    const float* __restrict__ bias, float* __restrict__ em)
{
    __shared__ __align__(16) float Xs[16][132];
    __shared__ __align__(16) float Ws[16][68];

    const int tid = threadIdx.x;
    const int m0  = blockIdx.x * 128;
    const int tm  = tid >> 4;
    const int tn  = tid & 15;
    const int lm  = tid >> 2;
    const int lkq = tid & 3;
    const int wt  = tid & 63;
    const int wkq = tid >> 6;

    float acc[8][4];
#pragma unroll
    for (int i = 0; i < 8; i++)
#pragma unroll
        for (int j = 0; j < 4; j++) acc[i][j] = 0.f;

    float4 xr0, xr1, wr;
    xr0 = *(const float4*)&X[(size_t)(m0 + lm) * DD + lkq * 4];
    xr1 = *(const float4*)&X[(size_t)(m0 + lm + 64) * DD + lkq * 4];
    wr  = *(const float4*)&W[(size_t)wt * DD + wkq * 4];

    for (int t = 0; t < 48; t++) {
        Xs[lkq * 4 + 0][lm] = xr0.x;  Xs[lkq * 4 + 1][lm] = xr0.y;
        Xs[lkq * 4 + 2][lm] = xr0.z;  Xs[lkq * 4 + 3][lm] = xr0.w;
        Xs[lkq * 4 + 0][lm + 64] = xr1.x;  Xs[lkq * 4 + 1][lm + 64] = xr1.y;
        Xs[lkq * 4 + 2][lm + 64] = xr1.z;  Xs[lkq * 4 + 3][lm + 64] = xr1.w;
        Ws[wkq * 4 + 0][wt] = wr.x;  Ws[wkq * 4 + 1][wt] = wr.y;
        Ws[wkq * 4 + 2][wt] = wr.z;  Ws[wkq * 4 + 3][wt] = wr.w;
        __syncthreads();

        if (t < 47) {
            const int k0 = (t + 1) * 16;
            xr0 = *(const float4*)&X[(size_t)(m0 + lm) * DD + k0 + lkq * 4];
            xr1 = *(const float4*)&X[(size_t)(m0 + lm + 64) * DD + k0 + lkq * 4];
            wr  = *(const float4*)&W[(size_t)wt * DD + k0 + wkq * 4];
        }

#pragma unroll
        for (int k = 0; k < 16; k++) {
            float a[8], bv[4];
            *(float4*)&a[0] = *(const float4*)&Xs[k][tm * 8];
            *(float4*)&a[4] = *(const float4*)&Xs[k][tm * 8 + 4];
            *(float4*)&bv[0] = *(const float4*)&Ws[k][tn * 4];
#pragma unroll
            for (int i = 0; i < 8; i++)
#pragma unroll
                for (int j = 0; j < 4; j++)
                    acc[i][j] = fmaf(a[i], bv[j], acc[i][j]);
        }
        __syncthreads();
    }

    const float4 bv4 = *(const float4*)&bias[tn * 4];
#pragma unroll
    for (int i = 0; i < 8; i++) {
        const size_t row = (size_t)(m0 + tm * 8 + i);
        float4 o;
        o.x = acc[i][0] + bv4.x;  o.y = acc[i][1] + bv4.y;
        o.z = acc[i][2] + bv4.z;  o.w = acc[i][3] + bv4.w;
        *(float4*)&em[row * TT + tn * 4] = o;
    }
}

// ---------------------------------------------------------------------------
// Kernel 2: Viterbi forward, VALUE ONLY. One wave per batch (64 x 64).
// new_score[cur] = round(max_p round(score[p]+trans[p][cur]) + em[cur])
// == reference's max of round(round(s+t)+em) bit-exact (rounding is
// monotone; adding the lane-constant em commutes with max). No argmax here
// -- backpointers are recomputed in parallel by bp_kernel from the stored
// score history. Per step: 64 adds + max3 tree (~32) + 1 add + 16 ds_read
// + 1 ds_write + 1 score store.  Minimal single-wave issue count.
// ---------------------------------------------------------------------------
__global__ __launch_bounds__(64, 1) void viterbi_fwd(
    const float* __restrict__ em, const float* __restrict__ trans,
    float* __restrict__ scoreHist, int* __restrict__ bestTag)
{
    __shared__ __align__(16) float sc_lds[TT];

    const int b    = blockIdx.x;
    const int lane = threadIdx.x;
    const float* emb = em + (size_t)b * SS * TT;
    float* sh = scoreHist + (size_t)b * SS * TT;

    float treg[TT];
#pragma unroll
    for (int p = 0; p < TT; p++) treg[p] = trans[p * TT + lane];

    const float em0 = emb[lane];
    sc_lds[lane] = em0;
    sh[lane] = em0;  // score_0
    float cur_score = em0;

    float er0 = emb[1 * TT + lane];
    float er1 = emb[2 * TT + lane];
    float er2 = emb[3 * TT + lane];
    float er3 = emb[4 * TT + lane];

    float4 sq[16];
    {
        const float4* sb = (const float4*)sc_lds;
#pragma unroll
        for (int i = 0; i < 16; i++) sq[i] = sb[i];
    }

    auto step = [&](int s, float em_v) {
        float v[TT];
#pragma unroll
        for (int i = 0; i < 16; i++) {
            v[4 * i + 0] = sq[i].x + treg[4 * i + 0];
            v[4 * i + 1] = sq[i].y + treg[4 * i + 1];
            v[4 * i + 2] = sq[i].z + treg[4 * i + 2];
            v[4 * i + 3] = sq[i].w + treg[4 * i + 3];
        }
        // max3 tree, depth 4, value only
        float t1[22];
#pragma unroll
        for (int i = 0; i < 21; i++)
            t1[i] = fmaxf(fmaxf(v[3 * i], v[3 * i + 1]), v[3 * i + 2]);
        t1[21] = v[63];
        float t2[8];
#pragma unroll
        for (int i = 0; i < 7; i++)
            t2[i] = fmaxf(fmaxf(t1[3 * i], t1[3 * i + 1]), t1[3 * i + 2]);
        t2[7] = t1[21];
        float t3[3];
        t3[0] = fmaxf(fmaxf(t2[0], t2[1]), t2[2]);
        t3[1] = fmaxf(fmaxf(t2[3], t2[4]), t2[5]);
        t3[2] = fmaxf(t2[6], t2[7]);
        const float sc = fmaxf(fmaxf(t3[0], t3[1]), t3[2]) + em_v;

        cur_score = sc;
        sc_lds[lane] = sc;                  // end of serial chain
        {                                   // issue next step's reads NOW
            const float4* sb = (const float4*)sc_lds;
#pragma unroll
            for (int i = 0; i < 16; i++) sq[i] = sb[i];
        }
        sh[s * TT + lane] = sc;             // score history for bp_kernel
    };

    for (int sb = 1; sb <= 505; sb += 4) {
        step(sb + 0, er0);  er0 = emb[(sb + 4) * TT + lane];
        step(sb + 1, er1);  er1 = emb[(sb + 5) * TT + lane];
        step(sb + 2, er2);  er2 = emb[(sb + 6) * TT + lane];
        step(sb + 3, er3);  er3 = emb[((sb + 7) <= 511 ? (sb + 7) : 511) * TT + lane];
    }
    step(509, er0);
    step(510, er1);
    step(511, er2);

    // final argmax across lanes (first-index ties)
    float fv = cur_score;
    int   fa = lane;
#pragma unroll
    for (int m = 1; m <= 32; m <<= 1) {
        const float vo = __shfl_xor(fv, m, 64);
        const int   ao = __shfl_xor(fa, m, 64);
        if (vo > fv || (vo == fv && ao < fa)) { fv = vo; fa = ao; }
    }
    if (lane == 0) bestTag[b] = fa;
}

// ---------------------------------------------------------------------------
// Kernel 3: backpointer recompute, massively parallel. One wave per (b,s),
// lane = cur. v[p] = (score_{s-1}[p] + trans[p][cur]) + em_s[cur] with
// exact reference rounding; left-wins tournament == first-index argmax.
// ---------------------------------------------------------------------------
__global__ __launch_bounds__(256) void bp_kernel(
    const float* __restrict__ scoreHist, const float* __restrict__ em,
    const float* __restrict__ trans, unsigned char* __restrict__ hist8)
{
    __shared__ __align__(16) float tr_lds[4096];  // 16 KB: trans[64][64]
    const int tid = threadIdx.x;
    {
        const float4* src = (const float4*)trans;
        float4* dst = (float4*)tr_lds;
        for (int i = tid; i < 1024; i += 256) dst[i] = src[i];
    }
    __syncthreads();

    const int wv   = tid >> 6;
    const int lane = tid & 63;
    const int g    = blockIdx.x * 4 + wv;   // 0..32703
    const int b    = g / 511;
    const int s    = 1 + (g % 511);

    const float4* sb4 = (const float4*)(scoreHist + ((size_t)b * SS + (s - 1)) * TT);
    const float em_v = em[((size_t)b * SS + s) * TT + lane];

    float treg[TT];
#pragma unroll
    for (int p = 0; p < TT; p++) treg[p] = tr_lds[p * TT + lane];

    float4 sq[16];
#pragma unroll
    for (int i = 0; i < 16; i++) sq[i] = sb4[i];

    float v[TT];
#pragma unroll
    for (int i = 0; i < 16; i++) {
        v[4 * i + 0] = (sq[i].x + treg[4 * i + 0]) + em_v;
        v[4 * i + 1] = (sq[i].y + treg[4 * i + 1]) + em_v;
        v[4 * i + 2] = (sq[i].z + treg[4 * i + 2]) + em_v;
        v[4 * i + 3] = (sq[i].w + treg[4 * i + 3]) + em_v;
    }
    // left-wins tournament (== numpy first-index argmax)
    float m1[32]; int a1[32];
#pragma unroll
    for (int i = 0; i < 32; i++) {
        const bool t = v[2 * i + 1] > v[2 * i];
        m1[i] = t ? v[2 * i + 1] : v[2 * i];
        a1[i] = 2 * i + (t ? 1 : 0);
    }
    float m2[16]; int a2[16];
#pragma unroll
    for (int i = 0; i < 16; i++) {
        const bool t = m1[2 * i + 1] > m1[2 * i];
        m2[i] = t ? m1[2 * i + 1] : m1[2 * i];
        a2[i] = t ? a1[2 * i + 1] : a1[2 * i];
    }
    float m3[8]; int a3[8];
#pragma unroll
    for (int i = 0; i < 8; i++) {
        const bool t = m2[2 * i + 1] > m2[2 * i];
        m3[i] = t ? m2[2 * i + 1] : m2[2 * i];
        a3[i] = t ? a2[2 * i + 1] : a2[2 * i];
    }
    float m4[4]; int a4[4];
#pragma unroll
    for (int i = 0; i < 4; i++) {
        const bool t = m3[2 * i + 1] > m3[2 * i];
        m4[i] = t ? m3[2 * i + 1] : m3[2 * i];
        a4[i] = t ? a3[2 * i + 1] : a3[2 * i];
    }
    float m5[2]; int a5[2];
#pragma unroll
    for (int i = 0; i < 2; i++) {
        const bool t = m4[2 * i + 1] > m4[2 * i];
        m5[i] = t ? m4[2 * i + 1] : m4[2 * i];
        a5[i] = t ? a4[2 * i + 1] : a4[2 * i];
    }
    const bool t6 = m5[1] > m5[0];
    const int barg = t6 ? a5[1] : a5[0];

    hist8[((size_t)b * SS + s) * TT + lane] = (unsigned char)barg;
}

// ---------------------------------------------------------------------------
// Kernel 4: backtrack via LDS path doubling, 1024 threads, 4-wide batched
// dependent loads. hist8 layout: [b][s][t], rows s=1..511 valid.
// ---------------------------------------------------------------------------
__global__ __launch_bounds__(1024) void backtrack(
    const unsigned char* __restrict__ hist8, const int* __restrict__ bestTag,
    int* __restrict__ out)
{
    __shared__ unsigned char A[511 * 64];
    __shared__ unsigned char Bf[511 * 64];

    const int b   = blockIdx.x;
    const int tid = threadIdx.x;
    const unsigned char* h8 = hist8 + (size_t)b * SS * TT;

    // G[s][t] = bp at s+1 given tag t: init from hist rows 1..511
    for (int idx = tid; idx < 511 * 64; idx += 1024) A[idx] = h8[idx + 64];
    __syncthreads();

    unsigned char* curT = A;
    unsigned char* nxtT = Bf;
    for (int d = 1; d < 511; d <<= 1) {
        // 32704 elems, 1024 threads -> 32 each; batches of 4 for ILP
        for (int gQ = 0; gQ < 7; gQ++) {
            int i0 = tid + (gQ * 4 + 0) * 1024;
            int i1 = tid + (gQ * 4 + 1) * 1024;
            int i2 = tid + (gQ * 4 + 2) * 1024;
            int i3 = tid + (gQ * 4 + 3) * 1024;
            int s0 = i0 >> 6, s1 = i1 >> 6, s2 = i2 >> 6, s3 = i3 >> 6;
            int a0 = (s0 + d >= 511) ? i0 : (s0 + d) * 64 + (i0 & 63);
            int a1 = (s1 + d >= 511) ? i1 : (s1 + d) * 64 + (i1 & 63);
            int a2 = (s2 + d >= 511) ? i2 : (s2 + d) * 64 + (i2 & 63);
            int a3 = (s3 + d >= 511) ? i3 : (s3 + d) * 64 + (i3 & 63);
            unsigned char q0 = curT[a0], q1 = curT[a1], q2 = curT[a2], q3 = curT[a3];
            int f0 = (s0 + d >= 511) ? i0 : s0 * 64 + q0;
            int f1 = (s1 + d >= 511) ? i1 : s1 * 64 + q1;
            int f2 = (s2 + d >= 511) ? i2 : s2 * 64 + q2;
            int f3 = (s3 + d >= 511) ? i3 : s3 * 64 + q3;
            nxtT[i0] = curT[f0];  nxtT[i1] = curT[f1];
            nxtT[i2] = curT[f2];  nxtT[i3] = curT[f3];
        }
        // j = 28,29,30 unguarded; j = 31 guarded
        for (int j = 28; j < 31; j++) {
            int i0 = tid + j * 1024;
            int s0 = i0 >> 6;
            int a0 = (s0 + d >= 511) ? i0 : (s0 + d) * 64 + (i0 & 63);
            unsigned char q0 = curT[a0];
            int f0 = (s0 + d >= 511) ? i0 : s0 * 64 + q0;
            nxtT[i0] = curT[f0];
        }
        {
            int i0 = tid + 31 * 1024;
            if (i0 < 511 * 64) {
                int s0 = i0 >> 6;
                int a0 = (s0 + d >= 511) ? i0 : (s0 + d) * 64 + (i0 & 63);
                unsigned char q0 = curT[a0];
                int f0 = (s0 + d >= 511) ? i0 : s0 * 64 + q0;
                nxtT[i0] = curT[f0];
            }
        }
        __syncthreads();
        unsigned char* tmp = curT; curT = nxtT; nxtT = tmp;
    }

    const int bt = bestTag[b];
    for (int s = tid; s < SS; s += 1024) {
        const int tag = (s == 511) ? bt : (int)curT[s * 64 + bt];
        out[(size_t)b * SS + s] = tag;
    }
}

// ---------------------------------------------------------------------------
extern "C" void kernel_launch(void* const* d_in, const int* in_sizes, int n_in,
                              void* d_out, int out_size, void* d_ws, size_t ws_size,
                              hipStream_t stream)
{
    const float* X     = (const float*)d_in[0];  // [64,512,768]
    const float* W     = (const float*)d_in[1];  // [64,768]
    const float* bias  = (const float*)d_in[2];  // [64]
    const float* trans = (const float*)d_in[3];  // [64,64]
    int* out = (int*)d_out;                      // [64,512] int32

    char* ws = (char*)d_ws;
    float*         em        = (float*)ws;                      // 8,388,608 B
    float*         scoreHist = (float*)(ws + 8388608);          // 8,388,608 B
    unsigned char* hist8     = (unsigned char*)(ws + 16777216); // 2,097,152 B
    int*           bestTag   = (int*)(ws + 18874368);           // 256 B

    emis_gemm<<<dim3(256), dim3(256), 0, stream>>>(X, W, bias, em);
    viterbi_fwd<<<dim3(64), dim3(64), 0, stream>>>(em, trans, scoreHist, bestTag);
    bp_kernel<<<dim3(8176), dim3(256), 0, stream>>>(scoreHist, em, trans, hist8);
    backtrack<<<dim3(64), dim3(1024), 0, stream>>>(hist8, bestTag, out);
}